// Round 2
// baseline (15108.052 us; speedup 1.0000x reference)
//
#include <hip/hip_runtime.h>
#include <hip/hip_bf16.h>
#include <hip/hip_cooperative_groups.h>

namespace cg = cooperative_groups;

// LSTM decoder w/ argmax feedback. V=10000 E=512 H=512 B=64 T=128.
// Persistent cooperative kernel: whole 127-step loop in ONE dispatch with
// grid.sync() between phases. Cell weights/base/c live in LDS (preloaded
// once). Accumulation order bitwise-identical to the verified multi-launch
// version (kept as fallback).

#define VSZ 10000
#define ESZ 512
#define HSZ 512
#define BSZ 64
#define TSZ 128
#define NSTEP (TSZ - 1)
#define NTILE 157    // fallback path: ceil(10000/64) vocab tiles
#define NT16 625     // persistent path: 10000/16 row tiles

typedef short bf16x8 __attribute__((ext_vector_type(8)));
typedef float f32x4 __attribute__((ext_vector_type(4)));

struct alignas(8) us4_t { unsigned short s[4]; };

#define NEG_INF (-3.402823466e38f)
#define MFMA16(a, b, c) __builtin_amdgcn_mfma_f32_16x16x32_bf16((a), (b), (c), 0, 0, 0)

__device__ __forceinline__ float bf2f(unsigned short u) {
    union { unsigned int i; float f; } c;
    c.i = ((unsigned int)u) << 16;
    return c.f;
}
__device__ __forceinline__ unsigned short f2bf(float f) {
    union { float f; unsigned int i; } c;
    c.f = f;
    unsigned int b = c.i;
    b += 0x7FFFu + ((b >> 16) & 1u);   // RNE (finite inputs only)
    return (unsigned short)(b >> 16);
}
__device__ __forceinline__ float sigmoidf_(float x) {
    return 1.0f / (1.0f + expf(-x));
}
__device__ __forceinline__ int imin_(int a, int b) { return a < b ? a : b; }
__device__ __forceinline__ int imax_(int a, int b) { return a > b ? a : b; }

// split 8 fp32 into bf16 hi + bf16 lo; only used by fallback MODE2 A-path
__device__ __forceinline__ void split8(const float* p, bf16x8& hi, bf16x8& lo) {
    float4 x = *(const float4*)p;
    float4 y = *(const float4*)(p + 4);
    float v[8] = {x.x, x.y, x.z, x.w, y.x, y.y, y.z, y.w};
    #pragma unroll
    for (int j = 0; j < 8; j++) {
        unsigned short h = f2bf(v[j]);
        hi[j] = (short)h;
        lo[j] = (short)f2bf(v[j] - bf2f(h));
    }
}

// ---- detector: mode (fp32 vs bf16 float arrays) + use_label canonicalize ----
__global__ __launch_bounds__(256) void det_kernel(
        const void* wout, const void* usel_raw, int* flags, int* usel) {
    __shared__ int s_bad, s_cnt;
    int tid = threadIdx.x;
    if (tid == 0) { s_bad = 0; s_cnt = 0; }
    __syncthreads();
    unsigned short u = ((const unsigned short*)wout)[tid];
    int e = (u >> 7) & 0xFF;
    if (e >= 0x7D) atomicOr(&s_bad, 1);
    if (tid < 32) {
        int word = ((const int*)usel_raw)[tid];
        if (word == 0 || word == 1) atomicAdd(&s_cnt, 1);
    }
    __syncthreads();
    int mode = s_bad ? 1 : 0;
    int as_int = (s_cnt == 32) ? 1 : 0;
    if (tid == 0) { flags[0] = mode; flags[1] = as_int; }
    if (tid < TSZ) {
        int v;
        if (as_int) v = ((const int*)usel_raw)[tid];
        else        v = (int)((const unsigned char*)usel_raw)[tid];
        usel[tid] = v ? 1 : 0;
    }
}

// ---- one-time weight split (mode 1 only): fp32 -> bf16 hi/lo ----
__global__ __launch_bounds__(256) void splitw_kernel(
        const float* __restrict__ src, unsigned short* __restrict__ hi,
        unsigned short* __restrict__ lo, int n8, int rowStride, int colOff,
        const int* __restrict__ flags) {
    if (flags[0] == 0) return;
    int i = blockIdx.x * 256 + threadIdx.x;
    if (i >= n8) return;
    int row = i >> 6;
    int ch = i & 63;
    const float* p = src + (size_t)row * rowStride + colOff + ch * 8;
    float4 x = *(const float4*)p;
    float4 y = *(const float4*)(p + 4);
    float v[8] = {x.x, x.y, x.z, x.w, y.x, y.y, y.z, y.w};
    us4_t h4[2], l4[2];
    #pragma unroll
    for (int j = 0; j < 8; j++) {
        unsigned short h = f2bf(v[j]);
        h4[j >> 2].s[j & 3] = h;
        l4[j >> 2].s[j & 3] = f2bf(v[j] - bf2f(h));
    }
    size_t o = (size_t)row * 512 + ch * 8;
    *(us4_t*)(hi + o) = h4[0];
    *(us4_t*)(hi + o + 4) = h4[1];
    *(us4_t*)(lo + o) = l4[0];
    *(us4_t*)(lo + o + 4) = l4[1];
}

// ---- base[g,b] = b_ih[g]+b_hh[g]+ctx[b,:]@W_ih[g,0:512]; lives in d_out t=0 slice ----
__global__ __launch_bounds__(256) void base_kernel(
        const void* ctx, const void* Wih, const void* bih, const void* bhh,
        const int* flags, char* outb) {
    int tid = threadIdx.x;
    int b = tid & 63;
    int gi = tid >> 6;
    int g = blockIdx.x * 4 + gi;
    float acc;
    size_t rowb;
    if (flags[0] == 0) {
        rowb = 2560000u;
        const unsigned short* wr = (const unsigned short*)Wih + (size_t)g * 1024;
        const unsigned short* cr = (const unsigned short*)ctx + (size_t)b * HSZ;
        acc = bf2f(((const unsigned short*)bih)[g]) + bf2f(((const unsigned short*)bhh)[g]);
        for (int k = 0; k < HSZ; k += 8) {
            #pragma unroll
            for (int u = 0; u < 8; u++) acc += bf2f(cr[k + u]) * bf2f(wr[k + u]);
        }
    } else {
        rowb = 5120000u;
        const float* wr = (const float*)Wih + (size_t)g * 1024;
        const float* cr = (const float*)ctx + (size_t)b * HSZ;
        acc = ((const float*)bih)[g] + ((const float*)bhh)[g];
        for (int k = 0; k < HSZ; k += 8) {
            #pragma unroll
            for (int u = 0; u < 8; u++) acc += cr[k + u] * wr[k + u];
        }
    }
    ((float*)(outb + (size_t)b * rowb))[g] = acc;
}

// ---- init: c=h0=ctx; h0/inp stored as pre-split bf16 hi/lo ----
__global__ __launch_bounds__(256) void init_kernel(
        const void* ctx, const void* emb, const int* labels, const int* flags,
        float* c, unsigned short* h0H, unsigned short* h0L,
        unsigned short* inpH, unsigned short* inpL) {
    int mode = flags[0];
    int i = blockIdx.x * 256 + threadIdx.x;   // 32768
    int b = i >> 9, j = i & 511;
    float cv = mode ? ((const float*)ctx)[i] : bf2f(((const unsigned short*)ctx)[i]);
    c[i] = cv;
    unsigned short hh = f2bf(cv);
    h0H[i] = hh;
    h0L[i] = f2bf(cv - bf2f(hh));
    int lab = imin_(imax_(labels[b * TSZ], 0), VSZ - 1);
    if (mode) {
        float e = ((const float*)emb)[(size_t)lab * ESZ + j];
        unsigned short eh = f2bf(e);
        inpH[i] = eh;
        inpL[i] = f2bf(e - bf2f(eh));
    } else {
        inpH[i] = ((const unsigned short*)emb)[(size_t)lab * ESZ + j];
    }
}

// ===================== PERSISTENT COOPERATIVE KERNEL ========================
// grid 256 x 256. Per step: CELL (blocks 0..127) -> sync -> OUT (625 tiles
// over all blocks) -> sync -> PICK (blocks 0..63) -> sync.
// Cell block = 4 j x 4 gates x 64 batch; weights (hi/lo), base, c in LDS.

template<int MODE>
__device__ __forceinline__ void persist_body(
        cg::grid_group& grid,
        const void* ctx, const int* labels, const void* emb,
        const void* Wih, const void* Whh, const void* Wout, const void* bout,
        const unsigned short* __restrict__ WoutH,
        const unsigned short* __restrict__ WoutL,
        char* outb,
        unsigned short* hA_H, unsigned short* hA_L,
        unsigned short* hB_H, unsigned short* hB_L,
        unsigned short* inpH, unsigned short* inpL,
        unsigned long long* pkey, const int* usel,
        unsigned short* wA,      // [2][32][16][4][8] = 32768 ushort (64 KB)
        float* bL,               // [16][64] base
        float* cL,               // [4][64] c state
        float* gb,               // [16][64] gate staging
        unsigned long long* rk,  // [256] pick reduce
        int* s_pred) {
    const size_t rowb = MODE ? 5120000u : 2560000u;
    int blk = blockIdx.x, tid = threadIdx.x;
    int wv = tid >> 6, lane = tid & 63, col = lane & 15, quad = lane >> 4;
    int j0 = (blk & 127) * 4;

    // ---- one-time preload: weight slice (split), base, c into LDS ----
    if (blk < 128) {
        for (int idx = tid; idx < 16 * 1024; idx += 256) {
            int ri = idx >> 10, k = idx & 1023;
            int g = ri >> 2, jj = ri & 3;
            int grow = g * 512 + j0 + jj;
            float v;
            if (MODE) {
                v = (k < 512) ? ((const float*)Wih)[(size_t)grow * 1024 + 512 + k]
                              : ((const float*)Whh)[(size_t)grow * 512 + (k - 512)];
            } else {
                unsigned short u = (k < 512)
                    ? ((const unsigned short*)Wih)[(size_t)grow * 1024 + 512 + k]
                    : ((const unsigned short*)Whh)[(size_t)grow * 512 + (k - 512)];
                v = bf2f(u);
            }
            unsigned short hh = f2bf(v);
            int it = k >> 5, q = (k >> 3) & 3, e = k & 7;
            int o = ((it * 16 + ri) * 4 + q) * 8 + e;
            wA[o] = hh;
            wA[16384 + o] = MODE ? f2bf(v - bf2f(hh)) : (unsigned short)0;
        }
        for (int idx = tid; idx < 1024; idx += 256) {
            int ri = idx >> 6, b = idx & 63;
            int g = ri >> 2, jj = ri & 3;
            bL[ri * 64 + b] = ((const float*)(outb + (size_t)b * rowb))[g * 512 + j0 + jj];
        }
        {
            int jj = tid >> 6, b = tid & 63;
            int i = b * 512 + j0 + jj;
            cL[jj * 64 + b] = MODE ? ((const float*)ctx)[i]
                                   : bf2f(((const unsigned short*)ctx)[i]);
        }
    }
    __syncthreads();

    for (int t = 0; t < NSTEP; ++t) {
        const unsigned short* hinH = (t & 1) ? hB_H : hA_H;
        const unsigned short* hinL = (t & 1) ? hB_L : hA_L;
        unsigned short* houtH = (t & 1) ? hA_H : hB_H;
        unsigned short* houtL = (t & 1) ? hA_L : hB_L;

        // ================= CELL =================
        if (blk < 128) {
            f32x4 acc = (f32x4){0.f, 0.f, 0.f, 0.f};
            const unsigned short* wa0 = wA + (col * 4 + quad) * 8;  // it stride 512
            int brow = (wv * 16 + col) * 512 + quad * 8;
            // ih part (W_ih cols 512..1023 vs inp)
            for (int it = 0; it < 16; ++it) {
                bf16x8 ah = *(const bf16x8*)(wa0 + it * 512);
                bf16x8 bh = *(const bf16x8*)(inpH + brow + it * 32);
                acc = MFMA16(ah, bh, acc);
                if (MODE) {
                    bf16x8 bl = *(const bf16x8*)(inpL + brow + it * 32);
                    acc = MFMA16(ah, bl, acc);
                    bf16x8 al = *(const bf16x8*)(wa0 + 16384 + it * 512);
                    acc = MFMA16(al, bh, acc);
                }
            }
            // hh part (W_hh vs h)
            for (int it = 0; it < 16; ++it) {
                bf16x8 ah = *(const bf16x8*)(wa0 + (16 + it) * 512);
                bf16x8 bh = *(const bf16x8*)(hinH + brow + it * 32);
                bf16x8 bl = *(const bf16x8*)(hinL + brow + it * 32);
                acc = MFMA16(ah, bh, acc);
                acc = MFMA16(ah, bl, acc);
                if (MODE) {
                    bf16x8 al = *(const bf16x8*)(wa0 + 16384 + (16 + it) * 512);
                    acc = MFMA16(al, bh, acc);
                }
            }
            // C/D: col=lane&15 -> batch-in-quarter, row=quad*4+r -> tile row
            #pragma unroll
            for (int r = 0; r < 4; ++r) {
                int ri = quad * 4 + r;
                int b = wv * 16 + col;
                gb[ri * 64 + b] = acc[r] + bL[ri * 64 + b];
            }
            __syncthreads();
            {
                int jj = tid >> 6, b = tid & 63;
                float iv = sigmoidf_(gb[(0 * 4 + jj) * 64 + b]);
                float fv = sigmoidf_(gb[(1 * 4 + jj) * 64 + b]);
                float gv = tanhf   (gb[(2 * 4 + jj) * 64 + b]);
                float ov = sigmoidf_(gb[(3 * 4 + jj) * 64 + b]);
                float c2 = fv * cL[jj * 64 + b] + iv * gv;
                cL[jj * 64 + b] = c2;
                float h2 = ov * tanhf(c2);
                unsigned short hh = f2bf(h2);
                houtH[b * 512 + j0 + jj] = hh;
                houtL[b * 512 + j0 + jj] = f2bf(h2 - bf2f(hh));
            }
        }
        grid.sync();

        // ================= OUT =================
        {
            int tile = wv * 256 + blk;
            if (tile < NT16) {
                f32x4 acc[4];
                #pragma unroll
                for (int nt = 0; nt < 4; nt++) acc[nt] = (f32x4){0.f, 0.f, 0.f, 0.f};
                int arow = tile * 16 + col;
                if (MODE) {
                    const unsigned short* AH = WoutH + (size_t)arow * 512 + quad * 8;
                    const unsigned short* AL = WoutL + (size_t)arow * 512 + quad * 8;
                    for (int k0 = 0; k0 < 512; k0 += 32) {
                        bf16x8 ah = *(const bf16x8*)(AH + k0);
                        bf16x8 al = *(const bf16x8*)(AL + k0);
                        #pragma unroll
                        for (int nt = 0; nt < 4; nt++) {
                            bf16x8 bh = *(const bf16x8*)(houtH + (nt * 16 + col) * 512 + k0 + quad * 8);
                            bf16x8 bl = *(const bf16x8*)(houtL + (nt * 16 + col) * 512 + k0 + quad * 8);
                            acc[nt] = MFMA16(ah, bh, acc[nt]);
                            acc[nt] = MFMA16(ah, bl, acc[nt]);
                            acc[nt] = MFMA16(al, bh, acc[nt]);
                        }
                    }
                } else {
                    const unsigned short* A = (const unsigned short*)Wout + (size_t)arow * 512 + quad * 8;
                    for (int k0 = 0; k0 < 512; k0 += 32) {
                        bf16x8 a = *(const bf16x8*)(A + k0);
                        #pragma unroll
                        for (int nt = 0; nt < 4; nt++) {
                            bf16x8 bh = *(const bf16x8*)(houtH + (nt * 16 + col) * 512 + k0 + quad * 8);
                            bf16x8 bl = *(const bf16x8*)(houtL + (nt * 16 + col) * 512 + k0 + quad * 8);
                            acc[nt] = MFMA16(a, bh, acc[nt]);
                            acc[nt] = MFMA16(a, bl, acc[nt]);
                        }
                    }
                }
                int vbase = tile * 16 + quad * 4;
                #pragma unroll
                for (int nt = 0; nt < 4; nt++) {
                    int b = nt * 16 + col;
                    float bv = NEG_INF;
                    int bi = 0;
                    float vals[4];
                    #pragma unroll
                    for (int r = 0; r < 4; r++) {
                        float bias = MODE ? ((const float*)bout)[vbase + r]
                                          : bf2f(((const unsigned short*)bout)[vbase + r]);
                        float val = acc[nt][r] + bias;
                        vals[r] = val;
                        if (val > bv) { bv = val; bi = vbase + r; }
                    }
                    size_t obase = ((size_t)b * TSZ + (t + 1)) * VSZ;
                    if (MODE) {
                        float4 f4;
                        f4.x = vals[0]; f4.y = vals[1]; f4.z = vals[2]; f4.w = vals[3];
                        *(float4*)((float*)outb + obase + vbase) = f4;
                    } else {
                        us4_t pack;
                        #pragma unroll
                        for (int r = 0; r < 4; r++) pack.s[r] = f2bf(vals[r]);
                        *(us4_t*)((unsigned short*)outb + obase + vbase) = pack;
                    }
                    #pragma unroll
                    for (int off = 16; off < 64; off <<= 1) {
                        float ov = __shfl_xor(bv, off);
                        int oi = __shfl_xor(bi, off);
                        if (ov > bv || (ov == bv && oi < bi)) { bv = ov; bi = oi; }
                    }
                    if (quad == 0) {
                        union { float f; unsigned u; } cv; cv.f = bv;
                        unsigned ob = (cv.u & 0x80000000u) ? ~cv.u : (cv.u | 0x80000000u);
                        pkey[(size_t)tile * 64 + b] =
                            ((unsigned long long)ob << 32) |
                            (unsigned long long)(0x7FFFFFFFu - (unsigned)bi);
                    }
                }
            }
        }
        grid.sync();

        // ================= PICK =================
        if (blk < 64) {
            int b = blk;
            unsigned long long best = 0ull;
            for (int tt = tid; tt < NT16; tt += 256) {
                unsigned long long kk = pkey[(size_t)tt * 64 + b];
                if (kk > best) best = kk;
            }
            rk[tid] = best;
            __syncthreads();
            for (int s = 128; s > 0; s >>= 1) {
                if (tid < s) { if (rk[tid + s] > rk[tid]) rk[tid] = rk[tid + s]; }
                __syncthreads();
            }
            if (tid == 0) {
                int ix = (int)(0x7FFFFFFFu - (unsigned)(rk[0] & 0xFFFFFFFFull));
                int lab = labels[b * TSZ + (t + 1)];
                int p = usel[t + 1] ? lab : ix;
                *s_pred = imin_(imax_(p, 0), VSZ - 1);
            }
            __syncthreads();
            int pr = *s_pred;
            if (tid < 128) {
                if (MODE) {
                    float4 f = ((const float4*)emb)[(size_t)pr * 128 + tid];
                    float vv[4] = {f.x, f.y, f.z, f.w};
                    us4_t h4, l4;
                    #pragma unroll
                    for (int r = 0; r < 4; r++) {
                        unsigned short hh = f2bf(vv[r]);
                        h4.s[r] = hh;
                        l4.s[r] = f2bf(vv[r] - bf2f(hh));
                    }
                    *(us4_t*)(inpH + (size_t)b * 512 + tid * 4) = h4;
                    *(us4_t*)(inpL + (size_t)b * 512 + tid * 4) = l4;
                } else {
                    us4_t u = ((const us4_t*)emb)[(size_t)pr * 128 + tid];
                    *(us4_t*)(inpH + (size_t)b * 512 + tid * 4) = u;
                }
            }
        }
        grid.sync();
    }
}

__global__ __launch_bounds__(256, 1) void persist_kernel(
        const void* ctx, const int* labels, const void* emb,
        const void* Wih, const void* Whh, const void* Wout, const void* bout,
        const unsigned short* WoutH, const unsigned short* WoutL,
        char* outb,
        unsigned short* h0H, unsigned short* h0L,
        unsigned short* h1H, unsigned short* h1L,
        unsigned short* inpH, unsigned short* inpL,
        unsigned long long* pkey, const int* usel, const int* flags) {
    cg::grid_group grid = cg::this_grid();
    __shared__ alignas(16) unsigned short wA[32768];   // 64 KB
    __shared__ float bL[1024];
    __shared__ float cL[256];
    __shared__ float gb[1024];
    __shared__ unsigned long long rk[256];
    __shared__ int s_pred;
    if (flags[0])
        persist_body<1>(grid, ctx, labels, emb, Wih, Whh, Wout, bout, WoutH, WoutL,
                        outb, h0H, h0L, h1H, h1L, inpH, inpL, pkey, usel,
                        wA, bL, cL, gb, rk, &s_pred);
    else
        persist_body<0>(grid, ctx, labels, emb, Wih, Whh, Wout, bout, WoutH, WoutL,
                        outb, h0H, h0L, h1H, h1L, inpH, inpL, pkey, usel,
                        wA, bL, cL, gb, rk, &s_pred);
}

// ===================== FALLBACK (verified multi-launch path) ================

template<int MODE>
__device__ __forceinline__ void cell_body(
        const void* Wih, const void* Whh,
        const unsigned short* __restrict__ WihH, const unsigned short* __restrict__ WihL,
        const unsigned short* __restrict__ WhhH, const unsigned short* __restrict__ WhhL,
        const char* outb,
        const unsigned short* __restrict__ inpH, const unsigned short* __restrict__ inpL,
        const unsigned short* __restrict__ hH, const unsigned short* __restrict__ hL,
        unsigned short* __restrict__ houtH, unsigned short* __restrict__ houtL,
        float* __restrict__ c) {
    __shared__ float lds[4][16][64];
    const size_t rowb = (MODE == 0) ? 2560000u : 5120000u;
    int tid = threadIdx.x;
    int w = tid >> 6;
    int lane = tid & 63;
    int col = lane & 15;
    int quad = lane >> 4;
    int ko = quad * 8;
    int j0 = blockIdx.x * 16;
    int grow = w * 512 + j0 + col;

    f32x4 acc[4];
    #pragma unroll
    for (int nt = 0; nt < 4; nt++) acc[nt] = (f32x4){0.f, 0.f, 0.f, 0.f};

    if (MODE == 0) {
        const unsigned short* A = (const unsigned short*)Wih + (size_t)grow * 1024 + 512 + ko;
        for (int k0 = 0; k0 < 512; k0 += 32) {
            bf16x8 a = *(const bf16x8*)(A + k0);
            #pragma unroll
            for (int nt = 0; nt < 4; nt++) {
                bf16x8 bh = *(const bf16x8*)(inpH + (nt * 16 + col) * 512 + k0 + ko);
                acc[nt] = MFMA16(a, bh, acc[nt]);
            }
        }
        const unsigned short* A2 = (const unsigned short*)Whh + (size_t)grow * 512 + ko;
        for (int k0 = 0; k0 < 512; k0 += 32) {
            bf16x8 a = *(const bf16x8*)(A2 + k0);
            #pragma unroll
            for (int nt = 0; nt < 4; nt++) {
                bf16x8 bh = *(const bf16x8*)(hH + (nt * 16 + col) * 512 + k0 + ko);
                bf16x8 bl = *(const bf16x8*)(hL + (nt * 16 + col) * 512 + k0 + ko);
                acc[nt] = MFMA16(a, bh, acc[nt]);
                acc[nt] = MFMA16(a, bl, acc[nt]);
            }
        }
    } else if (MODE == 1) {
        const unsigned short* AH = WihH + (size_t)grow * 512 + ko;
        const unsigned short* AL = WihL + (size_t)grow * 512 + ko;
        for (int k0 = 0; k0 < 512; k0 += 32) {
            bf16x8 ah = *(const bf16x8*)(AH + k0);
            bf16x8 al = *(const bf16x8*)(AL + k0);
            #pragma unroll
            for (int nt = 0; nt < 4; nt++) {
                bf16x8 bh = *(const bf16x8*)(inpH + (nt * 16 + col) * 512 + k0 + ko);
                bf16x8 bl = *(const bf16x8*)(inpL + (nt * 16 + col) * 512 + k0 + ko);
                acc[nt] = MFMA16(ah, bh, acc[nt]);
                acc[nt] = MFMA16(ah, bl, acc[nt]);
                acc[nt] = MFMA16(al, bh, acc[nt]);
            }
        }
        const unsigned short* AH2 = WhhH + (size_t)grow * 512 + ko;
        const unsigned short* AL2 = WhhL + (size_t)grow * 512 + ko;
        for (int k0 = 0; k0 < 512; k0 += 32) {
            bf16x8 ah = *(const bf16x8*)(AH2 + k0);
            bf16x8 al = *(const bf16x8*)(AL2 + k0);
            #pragma unroll
            for (int nt = 0; nt < 4; nt++) {
                bf16x8 bh = *(const bf16x8*)(hH + (nt * 16 + col) * 512 + k0 + ko);
                bf16x8 bl = *(const bf16x8*)(hL + (nt * 16 + col) * 512 + k0 + ko);
                acc[nt] = MFMA16(ah, bh, acc[nt]);
                acc[nt] = MFMA16(ah, bl, acc[nt]);
                acc[nt] = MFMA16(al, bh, acc[nt]);
            }
        }
    } else {
        const float* A = (const float*)Wih + (size_t)grow * 1024 + 512 + ko;
        for (int k0 = 0; k0 < 512; k0 += 32) {
            bf16x8 ah, al;
            split8(A + k0, ah, al);
            #pragma unroll
            for (int nt = 0; nt < 4; nt++) {
                bf16x8 bh = *(const bf16x8*)(inpH + (nt * 16 + col) * 512 + k0 + ko);
                bf16x8 bl = *(const bf16x8*)(inpL + (nt * 16 + col) * 512 + k0 + ko);
                acc[nt] = MFMA16(ah, bh, acc[nt]);
                acc[nt] = MFMA16(ah, bl, acc[nt]);
                acc[nt] = MFMA16(al, bh, acc[nt]);
            }
        }
        const float* A2 = (const float*)Whh + (size_t)grow * 512 + ko;
        for (int k0 = 0; k0 < 512; k0 += 32) {
            bf16x8 ah, al;
            split8(A2 + k0, ah, al);
            #pragma unroll
            for (int nt = 0; nt < 4; nt++) {
                bf16x8 bh = *(const bf16x8*)(hH + (nt * 16 + col) * 512 + k0 + ko);
                bf16x8 bl = *(const bf16x8*)(hL + (nt * 16 + col) * 512 + k0 + ko);
                acc[nt] = MFMA16(ah, bh, acc[nt]);
                acc[nt] = MFMA16(ah, bl, acc[nt]);
                acc[nt] = MFMA16(al, bh, acc[nt]);
            }
        }
    }
    #pragma unroll
    for (int nt = 0; nt < 4; nt++) {
        #pragma unroll
        for (int r = 0; r < 4; r++) {
            int row = quad * 4 + r;
            int b = nt * 16 + col;
            float bs = ((const float*)(outb + (size_t)b * rowb))[w * 512 + j0 + row];
            lds[w][row][b] = acc[nt][r] + bs;
        }
    }
    __syncthreads();
    for (int i = tid; i < 1024; i += 256) {
        int jl = i >> 6, b = i & 63, j = j0 + jl;
        float iv = sigmoidf_(lds[0][jl][b]);
        float fv = sigmoidf_(lds[1][jl][b]);
        float gv = tanhf(lds[2][jl][b]);
        float ov = sigmoidf_(lds[3][jl][b]);
        float c2 = fv * c[b * 512 + j] + iv * gv;
        c[b * 512 + j] = c2;
        float h2 = ov * tanhf(c2);
        unsigned short hh = f2bf(h2);
        houtH[b * 512 + j] = hh;
        houtL[b * 512 + j] = f2bf(h2 - bf2f(hh));
    }
}

__global__ __launch_bounds__(256) void cell_kernel(
        const void* Wih, const void* Whh, const char* outb,
        const unsigned short* WihH, const unsigned short* WihL,
        const unsigned short* WhhH, const unsigned short* WhhL,
        const unsigned short* inpH, const unsigned short* inpL,
        const unsigned short* hH, const unsigned short* hL,
        unsigned short* houtH, unsigned short* houtL,
        float* c, const int* flags, int presplit) {
    if (flags[0] == 0)
        cell_body<0>(Wih, Whh, WihH, WihL, WhhH, WhhL, outb, inpH, inpL, hH, hL, houtH, houtL, c);
    else if (presplit)
        cell_body<1>(Wih, Whh, WihH, WihL, WhhH, WhhL, outb, inpH, inpL, hH, hL, houtH, houtL, c);
    else
        cell_body<2>(Wih, Whh, WihH, WihL, WhhH, WhhL, outb, inpH, inpL, hH, hL, houtH, houtL, c);
}

template<int MODE>
__device__ __forceinline__ void out_body(
        const void* Wout, const unsigned short* __restrict__ WoutH,
        const unsigned short* __restrict__ WoutL, const void* bout,
        const unsigned short* __restrict__ hH, const unsigned short* __restrict__ hL,
        void* outv, float* pval, int* pidx, int t) {
    __shared__ float sv[4][64];
    __shared__ int   si[4][64];
    int tid = threadIdx.x;
    int w = tid >> 6, lane = tid & 63, col = lane & 15, quad = lane >> 4;
    int ko = quad * 8;
    int v0 = blockIdx.x * 64 + w * 16;
    int arow = imin_(v0 + col, VSZ - 1);

    f32x4 acc[4];
    #pragma unroll
    for (int nt = 0; nt < 4; nt++) acc[nt] = (f32x4){0.f, 0.f, 0.f, 0.f};

    if (MODE == 0) {
        const unsigned short* A = (const unsigned short*)Wout + (size_t)arow * 512 + ko;
        for (int k0 = 0; k0 < 512; k0 += 32) {
            bf16x8 a = *(const bf16x8*)(A + k0);
            #pragma unroll
            for (int nt = 0; nt < 4; nt++) {
                bf16x8 bh = *(const bf16x8*)(hH + (nt * 16 + col) * 512 + k0 + ko);
                bf16x8 bl = *(const bf16x8*)(hL + (nt * 16 + col) * 512 + k0 + ko);
                acc[nt] = MFMA16(a, bh, acc[nt]);
                acc[nt] = MFMA16(a, bl, acc[nt]);
            }
        }
    } else if (MODE == 1) {
        const unsigned short* AH = WoutH + (size_t)arow * 512 + ko;
        const unsigned short* AL = WoutL + (size_t)arow * 512 + ko;
        for (int k0 = 0; k0 < 512; k0 += 32) {
            bf16x8 ah = *(const bf16x8*)(AH + k0);
            bf16x8 al = *(const bf16x8*)(AL + k0);
            #pragma unroll
            for (int nt = 0; nt < 4; nt++) {
                bf16x8 bh = *(const bf16x8*)(hH + (nt * 16 + col) * 512 + k0 + ko);
                bf16x8 bl = *(const bf16x8*)(hL + (nt * 16 + col) * 512 + k0 + ko);
                acc[nt] = MFMA16(ah, bh, acc[nt]);
                acc[nt] = MFMA16(ah, bl, acc[nt]);
                acc[nt] = MFMA16(al, bh, acc[nt]);
            }
        }
    } else {
        const float* A = (const float*)Wout + (size_t)arow * 512 + ko;
        for (int k0 = 0; k0 < 512; k0 += 32) {
            bf16x8 ah, al;
            split8(A + k0, ah, al);
            #pragma unroll
            for (int nt = 0; nt < 4; nt++) {
                bf16x8 bh = *(const bf16x8*)(hH + (nt * 16 + col) * 512 + k0 + ko);
                bf16x8 bl = *(const bf16x8*)(hL + (nt * 16 + col) * 512 + k0 + ko);
                acc[nt] = MFMA16(ah, bh, acc[nt]);
                acc[nt] = MFMA16(ah, bl, acc[nt]);
                acc[nt] = MFMA16(al, bh, acc[nt]);
            }
        }
    }

    int vbase = v0 + quad * 4;
    #pragma unroll
    for (int nt = 0; nt < 4; nt++) {
        int b = nt * 16 + col;
        float bv = NEG_INF;
        int bi = 0;
        float vals[4];
        #pragma unroll
        for (int r = 0; r < 4; r++) {
            int v = vbase + r;
            int vc = imin_(v, VSZ - 1);
            float bias = (MODE != 0) ? ((const float*)bout)[vc]
                                     : bf2f(((const unsigned short*)bout)[vc]);
            float val = acc[nt][r] + bias;
            vals[r] = val;
            if (v < VSZ && val > bv) { bv = val; bi = v; }
        }
        size_t obase = ((size_t)b * TSZ + t) * VSZ;
        if (MODE == 0) {
            us4_t pack;
            #pragma unroll
            for (int r = 0; r < 4; r++) pack.s[r] = f2bf(vals[r]);
            if (vbase + 3 < VSZ) {
                *(us4_t*)((unsigned short*)outv + obase + vbase) = pack;
            } else {
                for (int r = 0; r < 4; r++)
                    if (vbase + r < VSZ) ((unsigned short*)outv)[obase + vbase + r] = pack.s[r];
            }
        } else {
            if (vbase + 3 < VSZ) {
                float4 f4; f4.x = vals[0]; f4.y = vals[1]; f4.z = vals[2]; f4.w = vals[3];
                *(float4*)((float*)outv + obase + vbase) = f4;
            } else {
                for (int r = 0; r < 4; r++)
                    if (vbase + r < VSZ) ((float*)outv)[obase + vbase + r] = vals[r];
            }
        }
        #pragma unroll
        for (int off = 16; off < 64; off <<= 1) {
            float ov = __shfl_xor(bv, off);
            int oi = __shfl_xor(bi, off);
            if (ov > bv || (ov == bv && oi < bi)) { bv = ov; bi = oi; }
        }
        if (quad == 0) { sv[w][b] = bv; si[w][b] = bi; }
    }
    __syncthreads();
    if (tid < 64) {
        float bv = sv[0][tid];
        int bi = si[0][tid];
        #pragma unroll
        for (int w2 = 1; w2 < 4; w2++) {
            float v2 = sv[w2][tid];
            int i2 = si[w2][tid];
            if (v2 > bv || (v2 == bv && i2 < bi)) { bv = v2; bi = i2; }
        }
        pval[blockIdx.x * 64 + tid] = bv;
        pidx[blockIdx.x * 64 + tid] = bi;
    }
}

__global__ __launch_bounds__(256) void out_kernel(
        const void* Wout, const unsigned short* WoutH, const unsigned short* WoutL,
        const void* bout, const unsigned short* hH, const unsigned short* hL,
        void* outv, float* pval, int* pidx, int t, const int* flags, int presplit) {
    if (flags[0] == 0)
        out_body<0>(Wout, WoutH, WoutL, bout, hH, hL, outv, pval, pidx, t);
    else if (presplit)
        out_body<1>(Wout, WoutH, WoutL, bout, hH, hL, outv, pval, pidx, t);
    else
        out_body<2>(Wout, WoutH, WoutL, bout, hH, hL, outv, pval, pidx, t);
}

__global__ __launch_bounds__(1024) void pick_kernel(
        const float* __restrict__ pval, const int* __restrict__ pidx,
        const void* emb, const int* __restrict__ labels,
        const int* __restrict__ usel, unsigned short* __restrict__ inpH,
        unsigned short* __restrict__ inpL, int t, const int* __restrict__ flags) {
    __shared__ float svv[64][4];
    __shared__ int   sii[64][4];
    __shared__ int   pred[64];
    int mode = flags[0];
    int tid = threadIdx.x;
    if (tid < 256) {
        int b = tid >> 2, q = tid & 3;
        float bv = NEG_INF;
        int bi = 0;
        for (int wt = q; wt < NTILE; wt += 4) {
            float v = pval[wt * 64 + b];
            int ix = pidx[wt * 64 + b];
            if (v > bv || (v == bv && ix < bi)) { bv = v; bi = ix; }
        }
        svv[b][q] = bv;
        sii[b][q] = bi;
    }
    __syncthreads();
    if (tid < 64) {
        float v = svv[tid][0];
        int ix = sii[tid][0];
        #pragma unroll
        for (int q2 = 1; q2 < 4; q2++) {
            float v2 = svv[tid][q2];
            int i2 = sii[tid][q2];
            if (v2 > v || (v2 == v && i2 < ix)) { v = v2; ix = i2; }
        }
        int lab = labels[tid * TSZ + t];
        int p = usel[t] ? lab : ix;
        pred[tid] = imin_(imax_(p, 0), VSZ - 1);
    }
    __syncthreads();
    for (int i = tid; i < BSZ * ESZ / 4; i += 1024) {
        int b2 = i >> 7;
        int ch = i & 127;
        if (mode) {
            float4 f = ((const float4*)emb)[(size_t)pred[b2] * 128 + ch];
            float vv[4] = {f.x, f.y, f.z, f.w};
            us4_t h4, l4;
            #pragma unroll
            for (int r = 0; r < 4; r++) {
                unsigned short hh = f2bf(vv[r]);
                h4.s[r] = hh;
                l4.s[r] = f2bf(vv[r] - bf2f(hh));
            }
            *(us4_t*)(inpH + (size_t)b2 * 512 + ch * 4) = h4;
            *(us4_t*)(inpL + (size_t)b2 * 512 + ch * 4) = l4;
        } else {
            us4_t u = ((const us4_t*)emb)[(size_t)pred[b2] * 128 + ch];
            *(us4_t*)(inpH + (size_t)b2 * 512 + ch * 4) = u;
        }
    }
}

// ---- zero the t=0 output slice (also wipes the base scratch living there) ----
__global__ void zero_t0_kernel(char* outb, const int* flags) {
    int i = blockIdx.x * 256 + threadIdx.x;
    uint4 z = make_uint4(0u, 0u, 0u, 0u);
    if (flags[0]) {
        if (i < 160000) {
            int b = i / 2500, ch = i - b * 2500;
            *((uint4*)(outb + (size_t)b * 5120000u) + ch) = z;
        }
    } else {
        if (i < 80000) {
            int b = i / 1250, ch = i - b * 1250;
            *((uint4*)(outb + (size_t)b * 2560000u) + ch) = z;
        }
    }
}

extern "C" void kernel_launch(void* const* d_in, const int* in_sizes, int n_in,
                              void* d_out, int out_size, void* d_ws, size_t ws_size,
                              hipStream_t stream) {
    const void* ctx      = d_in[0];
    const int*  labels   = (const int*)d_in[1];
    const void* usel_raw = d_in[2];
    const void* emb      = d_in[3];
    const void* Wih      = d_in[4];
    const void* Whh      = d_in[5];
    const void* bih      = d_in[6];
    const void* bhh      = d_in[7];
    const void* Wout     = d_in[8];
    const void* bout     = d_in[9];
    char* outb = (char*)d_out;

    char* ws = (char*)d_ws;
    // small region (as before)
    int*   flags = (int*)ws;                               // 256 B
    int*   usel  = (int*)(ws + 256);                       // 512 B
    float* pval  = (float*)(ws + 1024);                    // 40192
    int*   pidx  = (int*)(ws + 41216);                     // 40192
    float* c     = (float*)(ws + 81408);                   // 131072
    unsigned short* h0H  = (unsigned short*)(ws + 212480); // 65536
    unsigned short* h0L  = (unsigned short*)(ws + 278016); // 65536
    unsigned short* h1H  = (unsigned short*)(ws + 343552); // 65536
    unsigned short* h1L  = (unsigned short*)(ws + 409088); // 65536
    unsigned short* inpH = (unsigned short*)(ws + 474624); // 65536
    unsigned short* inpL = (unsigned short*)(ws + 540160); // 65536
    // persistent-path region
    unsigned long long* pkey = (unsigned long long*)(ws + 605696);  // 320,000
    unsigned short* WoutH = (unsigned short*)(ws + 925696);     // 10,240,000
    unsigned short* WoutL = (unsigned short*)(ws + 11165696);   // 10,240,000
    unsigned short* WihH  = (unsigned short*)(ws + 21405696);   //  2,097,152
    unsigned short* WihL  = (unsigned short*)(ws + 23502848);   //  2,097,152
    unsigned short* WhhH  = (unsigned short*)(ws + 25600000);   //  2,097,152
    unsigned short* WhhL  = (unsigned short*)(ws + 27697152);   //  2,097,152
    const size_t WS_FULL = 29794304u;
    int full = (ws_size >= WS_FULL) ? 1 : 0;

    det_kernel<<<1, 256, 0, stream>>>(Wout, usel_raw, flags, usel);
    if (full) {
        // no-ops in mode 0 (kernels early-out on flags)
        splitw_kernel<<<2500, 256, 0, stream>>>((const float*)Wout, WoutH, WoutL,
                                                VSZ * 64, 512, 0, flags);
        splitw_kernel<<<512, 256, 0, stream>>>((const float*)Wih, WihH, WihL,
                                               2048 * 64, 1024, 512, flags);
        splitw_kernel<<<512, 256, 0, stream>>>((const float*)Whh, WhhH, WhhL,
                                               2048 * 64, 512, 0, flags);
    }
    base_kernel<<<512, 256, 0, stream>>>(ctx, Wih, bih, bhh, flags, outb);
    init_kernel<<<128, 256, 0, stream>>>(ctx, emb, labels, flags, c, h0H, h0L, inpH, inpL);

    int did_persist = 0;
    if (full) {
        const void* a0 = ctx; const int* a1 = labels; const void* a2 = emb;
        const void* a3 = Wih; const void* a4 = Whh; const void* a5 = Wout;
        const void* a6 = bout;
        const unsigned short* a7 = WoutH; const unsigned short* a8 = WoutL;
        char* a9 = outb;
        unsigned short* a10 = h0H; unsigned short* a11 = h0L;
        unsigned short* a12 = h1H; unsigned short* a13 = h1L;
        unsigned short* a14 = inpH; unsigned short* a15 = inpL;
        unsigned long long* a16 = pkey; const int* a17 = usel; const int* a18 = flags;
        void* kargs[] = {&a0, &a1, &a2, &a3, &a4, &a5, &a6, &a7, &a8, &a9,
                         &a10, &a11, &a12, &a13, &a14, &a15, &a16, &a17, &a18};
        hipError_t e = hipLaunchCooperativeKernel(persist_kernel, dim3(256), dim3(256),
                                                  kargs, 0u, stream);
        if (e == hipSuccess) did_persist = 1;
    }
    if (!did_persist) {
        for (int k = 0; k < NSTEP; ++k) {
            unsigned short* hinH  = (k & 1) ? h1H : h0H;
            unsigned short* hinL  = (k & 1) ? h1L : h0L;
            unsigned short* houtH = (k & 1) ? h0H : h1H;
            unsigned short* houtL = (k & 1) ? h0L : h1L;
            cell_kernel<<<32, 256, 0, stream>>>(Wih, Whh, outb, WihH, WihL, WhhH, WhhL,
                                                inpH, inpL, hinH, hinL, houtH, houtL,
                                                c, flags, full);
            out_kernel<<<NTILE, 256, 0, stream>>>(Wout, WoutH, WoutL, bout, houtH, houtL,
                                                  (void*)outb, pval, pidx, k + 1,
                                                  flags, full);
            pick_kernel<<<1, 1024, 0, stream>>>(pval, pidx, emb, labels, usel, inpH, inpL,
                                                k + 1, flags);
        }
    }
    zero_t0_kernel<<<626, 256, 0, stream>>>(outb, flags);
}

// Round 3
// 7939.840 us; speedup vs baseline: 1.9028x; 1.9028x over previous
//
#include <hip/hip_runtime.h>
#include <hip/hip_bf16.h>
#include <hip/hip_cooperative_groups.h>

// LSTM decoder w/ argmax feedback. V=10000 E=512 H=512 B=64 T=128.
// Persistent two-pool kernel with custom flag barriers (no grid.sync):
//   P pool (blocks 0..127): LSTM cell, weights/base/c in LDS, pred reduce,
//     ih-GEMM B-operand gathered straight from pre-split embH/embL.
//   Q pool (blocks 128..255): logits tiles + block argmax -> bkey.
// Per step: P waits h_cnt[k-1]; feedback steps wait q_cnt[k-1]; label steps
// only lag-wait q_cnt[k-2] (Q overlaps with next cell). Arithmetic bitwise
// identical to the verified multi-launch path (kept as fallback).

#define VSZ 10000
#define ESZ 512
#define HSZ 512
#define BSZ 64
#define TSZ 128
#define NSTEP (TSZ - 1)
#define NTILE 157    // fallback path: ceil(10000/64) vocab tiles
#define NT16 625     // persistent path: 10000/16 row tiles

typedef short bf16x8 __attribute__((ext_vector_type(8)));
typedef float f32x4 __attribute__((ext_vector_type(4)));

struct alignas(8) us4_t { unsigned short s[4]; };

#define NEG_INF (-3.402823466e38f)
#define MFMA16(a, b, c) __builtin_amdgcn_mfma_f32_16x16x32_bf16((a), (b), (c), 0, 0, 0)

__device__ __forceinline__ float bf2f(unsigned short u) {
    union { unsigned int i; float f; } c;
    c.i = ((unsigned int)u) << 16;
    return c.f;
}
__device__ __forceinline__ unsigned short f2bf(float f) {
    union { float f; unsigned int i; } c;
    c.f = f;
    unsigned int b = c.i;
    b += 0x7FFFu + ((b >> 16) & 1u);   // RNE (finite inputs only)
    return (unsigned short)(b >> 16);
}
__device__ __forceinline__ float sigmoidf_(float x) {
    return 1.0f / (1.0f + expf(-x));
}
__device__ __forceinline__ int imin_(int a, int b) { return a < b ? a : b; }
__device__ __forceinline__ int imax_(int a, int b) { return a > b ? a : b; }

// split 8 fp32 into bf16 hi + bf16 lo; only used by fallback MODE2 A-path
__device__ __forceinline__ void split8(const float* p, bf16x8& hi, bf16x8& lo) {
    float4 x = *(const float4*)p;
    float4 y = *(const float4*)(p + 4);
    float v[8] = {x.x, x.y, x.z, x.w, y.x, y.y, y.z, y.w};
    #pragma unroll
    for (int j = 0; j < 8; j++) {
        unsigned short h = f2bf(v[j]);
        hi[j] = (short)h;
        lo[j] = (short)f2bf(v[j] - bf2f(h));
    }
}

// ---- lean block-level flag barrier primitives (agent scope) ----
__device__ __forceinline__ void sync_wait(int* p, int target) {
    if (threadIdx.x == 0) {
        while (__hip_atomic_load(p, __ATOMIC_RELAXED, __HIP_MEMORY_SCOPE_AGENT) < target)
            __builtin_amdgcn_s_sleep(1);
        (void)__hip_atomic_load(p, __ATOMIC_ACQUIRE, __HIP_MEMORY_SCOPE_AGENT);
    }
    __syncthreads();
}
__device__ __forceinline__ void sync_arrive(int* p) {
    __syncthreads();   // all block stores drained (compiler emits vmcnt(0) before barrier)
    if (threadIdx.x == 0)
        (void)__hip_atomic_fetch_add(p, 1, __ATOMIC_RELEASE, __HIP_MEMORY_SCOPE_AGENT);
}

// ---- detector: mode + use_label canonicalize + zero step counters ----
__global__ __launch_bounds__(256) void det_kernel(
        const void* wout, const void* usel_raw, int* flags, int* usel,
        int* h_cnt, int* q_cnt) {
    __shared__ int s_bad, s_cnt;
    int tid = threadIdx.x;
    if (tid == 0) { s_bad = 0; s_cnt = 0; }
    __syncthreads();
    unsigned short u = ((const unsigned short*)wout)[tid];
    int e = (u >> 7) & 0xFF;
    if (e >= 0x7D) atomicOr(&s_bad, 1);
    if (tid < 32) {
        int word = ((const int*)usel_raw)[tid];
        if (word == 0 || word == 1) atomicAdd(&s_cnt, 1);
    }
    __syncthreads();
    int mode = s_bad ? 1 : 0;
    int as_int = (s_cnt == 32) ? 1 : 0;
    if (tid == 0) { flags[0] = mode; flags[1] = as_int; }
    if (tid < TSZ) {
        int v;
        if (as_int) v = ((const int*)usel_raw)[tid];
        else        v = (int)((const unsigned char*)usel_raw)[tid];
        usel[tid] = v ? 1 : 0;
    }
    if (tid < TSZ) { h_cnt[tid] = 0; q_cnt[tid] = 0; }
}

// ---- one-time split (mode 1 only): fp32 -> bf16 hi/lo ----
__global__ __launch_bounds__(256) void splitw_kernel(
        const float* __restrict__ src, unsigned short* __restrict__ hi,
        unsigned short* __restrict__ lo, int n8, int rowStride, int colOff,
        const int* __restrict__ flags) {
    if (flags[0] == 0) return;
    int i = blockIdx.x * 256 + threadIdx.x;
    if (i >= n8) return;
    int row = i >> 6;
    int ch = i & 63;
    const float* p = src + (size_t)row * rowStride + colOff + ch * 8;
    float4 x = *(const float4*)p;
    float4 y = *(const float4*)(p + 4);
    float v[8] = {x.x, x.y, x.z, x.w, y.x, y.y, y.z, y.w};
    us4_t h4[2], l4[2];
    #pragma unroll
    for (int j = 0; j < 8; j++) {
        unsigned short h = f2bf(v[j]);
        h4[j >> 2].s[j & 3] = h;
        l4[j >> 2].s[j & 3] = f2bf(v[j] - bf2f(h));
    }
    size_t o = (size_t)row * 512 + ch * 8;
    *(us4_t*)(hi + o) = h4[0];
    *(us4_t*)(hi + o + 4) = h4[1];
    *(us4_t*)(lo + o) = l4[0];
    *(us4_t*)(lo + o + 4) = l4[1];
}

// ---- base[g,b] = b_ih[g]+b_hh[g]+ctx[b,:]@W_ih[g,0:512]; lives in d_out t=0 slice ----
__global__ __launch_bounds__(256) void base_kernel(
        const void* ctx, const void* Wih, const void* bih, const void* bhh,
        const int* flags, char* outb) {
    int tid = threadIdx.x;
    int b = tid & 63;
    int gi = tid >> 6;
    int g = blockIdx.x * 4 + gi;
    float acc;
    size_t rowb;
    if (flags[0] == 0) {
        rowb = 2560000u;
        const unsigned short* wr = (const unsigned short*)Wih + (size_t)g * 1024;
        const unsigned short* cr = (const unsigned short*)ctx + (size_t)b * HSZ;
        acc = bf2f(((const unsigned short*)bih)[g]) + bf2f(((const unsigned short*)bhh)[g]);
        for (int k = 0; k < HSZ; k += 8) {
            #pragma unroll
            for (int u = 0; u < 8; u++) acc += bf2f(cr[k + u]) * bf2f(wr[k + u]);
        }
    } else {
        rowb = 5120000u;
        const float* wr = (const float*)Wih + (size_t)g * 1024;
        const float* cr = (const float*)ctx + (size_t)b * HSZ;
        acc = ((const float*)bih)[g] + ((const float*)bhh)[g];
        for (int k = 0; k < HSZ; k += 8) {
            #pragma unroll
            for (int u = 0; u < 8; u++) acc += cr[k + u] * wr[k + u];
        }
    }
    ((float*)(outb + (size_t)b * rowb))[g] = acc;
}

// ---- init: c=h0=ctx; h0/inp stored as pre-split bf16 hi/lo ----
__global__ __launch_bounds__(256) void init_kernel(
        const void* ctx, const void* emb, const int* labels, const int* flags,
        float* c, unsigned short* h0H, unsigned short* h0L,
        unsigned short* inpH, unsigned short* inpL) {
    int mode = flags[0];
    int i = blockIdx.x * 256 + threadIdx.x;   // 32768
    int b = i >> 9, j = i & 511;
    float cv = mode ? ((const float*)ctx)[i] : bf2f(((const unsigned short*)ctx)[i]);
    c[i] = cv;
    unsigned short hh = f2bf(cv);
    h0H[i] = hh;
    h0L[i] = f2bf(cv - bf2f(hh));
    int lab = imin_(imax_(labels[b * TSZ], 0), VSZ - 1);
    if (mode) {
        float e = ((const float*)emb)[(size_t)lab * ESZ + j];
        unsigned short eh = f2bf(e);
        inpH[i] = eh;
        inpL[i] = f2bf(e - bf2f(eh));
    } else {
        inpH[i] = ((const unsigned short*)emb)[(size_t)lab * ESZ + j];
    }
}

// ===================== PERSISTENT TWO-POOL KERNEL ===========================

template<int MODE>
__device__ __forceinline__ void persist2_body(
        const void* ctx, const int* labels, const void* emb,
        const void* Wih, const void* Whh, const void* Wout, const void* bout,
        const unsigned short* __restrict__ WoutH, const unsigned short* __restrict__ WoutL,
        const unsigned short* __restrict__ embH, const unsigned short* __restrict__ embL,
        char* outb,
        unsigned short* hA_H, unsigned short* hA_L,
        unsigned short* hB_H, unsigned short* hB_L,
        unsigned long long* bkey, int* h_cnt, int* q_cnt, const int* usel,
        unsigned short* wA, float* bL, float* cL, float* gb,
        int* predL, unsigned long long* rv, unsigned long long* skey) {
    const size_t rowb = MODE ? 5120000u : 2560000u;
    int blk = blockIdx.x, tid = threadIdx.x;
    int wv = tid >> 6, lane = tid & 63, col = lane & 15, quad = lane >> 4;
    const unsigned short* ebH = MODE ? embH : (const unsigned short*)emb;

    if (blk < 128) {
        // ======================== P pool: cell + pred =======================
        int j0 = blk * 4;
        // one-time preload: weight slice (split), base, c into LDS
        for (int idx = tid; idx < 16 * 1024; idx += 256) {
            int ri = idx >> 10, k = idx & 1023;
            int g = ri >> 2, jj = ri & 3;
            int grow = g * 512 + j0 + jj;
            float v;
            if (MODE) {
                v = (k < 512) ? ((const float*)Wih)[(size_t)grow * 1024 + 512 + k]
                              : ((const float*)Whh)[(size_t)grow * 512 + (k - 512)];
            } else {
                unsigned short u = (k < 512)
                    ? ((const unsigned short*)Wih)[(size_t)grow * 1024 + 512 + k]
                    : ((const unsigned short*)Whh)[(size_t)grow * 512 + (k - 512)];
                v = bf2f(u);
            }
            unsigned short hh = f2bf(v);
            int it = k >> 5, q = (k >> 3) & 3, e = k & 7;
            int o = ((it * 16 + ri) * 4 + q) * 8 + e;
            wA[o] = hh;
            wA[16384 + o] = MODE ? f2bf(v - bf2f(hh)) : (unsigned short)0;
        }
        for (int idx = tid; idx < 1024; idx += 256) {
            int ri = idx >> 6, b = idx & 63;
            int g = ri >> 2, jj = ri & 3;
            bL[ri * 64 + b] = ((const float*)(outb + (size_t)b * rowb))[g * 512 + j0 + jj];
        }
        {
            int jj = tid >> 6, b = tid & 63;
            int i = b * 512 + j0 + jj;
            cL[jj * 64 + b] = MODE ? ((const float*)ctx)[i]
                                   : bf2f(((const unsigned short*)ctx)[i]);
        }
        __syncthreads();

        for (int k = 0; k < NSTEP; ++k) {
            const unsigned short* hinH = (k & 1) ? hB_H : hA_H;
            const unsigned short* hinL = (k & 1) ? hB_L : hA_L;
            unsigned short* houtH = (k & 1) ? hA_H : hB_H;
            unsigned short* houtL = (k & 1) ? hA_L : hB_L;

            if (k > 0) sync_wait(&h_cnt[k - 1], 128);   // h(k) visible (P barrier)
            int fb = (k > 0) && (usel[k] == 0);
            if (fb) {
                sync_wait(&q_cnt[k - 1], 128);          // argmax keys ready
                int b = tid >> 2, q = tid & 3;
                unsigned long long best = 0ull;
                for (int i = q; i < 128; i += 4) {
                    unsigned long long kk = bkey[i * 64 + b];
                    if (kk > best) best = kk;
                }
                rv[tid] = best;
                __syncthreads();
                if (tid < 64) {
                    unsigned long long b2 = rv[tid * 4];
                    #pragma unroll
                    for (int q2 = 1; q2 < 4; q2++) {
                        unsigned long long kk = rv[tid * 4 + q2];
                        if (kk > b2) b2 = kk;
                    }
                    int ix = (int)(0x7FFFFFFFu - (unsigned)(b2 & 0xFFFFFFFFull));
                    predL[tid] = imin_(imax_(ix, 0), VSZ - 1);
                }
            } else {
                if (k >= 2) sync_wait(&q_cnt[k - 2], 128);  // h-buffer reuse guard
                if (tid < 64) {
                    int lab = labels[tid * TSZ + k];
                    predL[tid] = imin_(imax_(lab, 0), VSZ - 1);
                }
            }
            __syncthreads();

            // -------- cell GEMM: LDS A, gathered emb B (ih), global h B (hh)
            f32x4 acc = (f32x4){0.f, 0.f, 0.f, 0.f};
            const unsigned short* wa0 = wA + (col * 4 + quad) * 8;
            int row = wv * 16 + col;                  // batch
            int pr = predL[row];
            const unsigned short* eH = ebH + (size_t)pr * 512 + quad * 8;
            const unsigned short* eL = embL + (size_t)pr * 512 + quad * 8;
            int brow = row * 512 + quad * 8;
            for (int it = 0; it < 16; ++it) {
                bf16x8 ah = *(const bf16x8*)(wa0 + it * 512);
                bf16x8 bh = *(const bf16x8*)(eH + it * 32);
                acc = MFMA16(ah, bh, acc);
                if (MODE) {
                    bf16x8 bl = *(const bf16x8*)(eL + it * 32);
                    acc = MFMA16(ah, bl, acc);
                    bf16x8 al = *(const bf16x8*)(wa0 + 16384 + it * 512);
                    acc = MFMA16(al, bh, acc);
                }
            }
            for (int it = 0; it < 16; ++it) {
                bf16x8 ah = *(const bf16x8*)(wa0 + (16 + it) * 512);
                bf16x8 bh = *(const bf16x8*)(hinH + brow + it * 32);
                bf16x8 bl = *(const bf16x8*)(hinL + brow + it * 32);
                acc = MFMA16(ah, bh, acc);
                acc = MFMA16(ah, bl, acc);
                if (MODE) {
                    bf16x8 al = *(const bf16x8*)(wa0 + 16384 + (16 + it) * 512);
                    acc = MFMA16(al, bh, acc);
                }
            }
            #pragma unroll
            for (int r = 0; r < 4; ++r) {
                int ri = quad * 4 + r;
                gb[ri * 64 + row] = acc[r] + bL[ri * 64 + row];
            }
            __syncthreads();
            {
                int jj = tid >> 6, b = tid & 63;
                float iv = sigmoidf_(gb[(0 * 4 + jj) * 64 + b]);
                float fv = sigmoidf_(gb[(1 * 4 + jj) * 64 + b]);
                float gv = tanhf   (gb[(2 * 4 + jj) * 64 + b]);
                float ov = sigmoidf_(gb[(3 * 4 + jj) * 64 + b]);
                float c2 = fv * cL[jj * 64 + b] + iv * gv;
                cL[jj * 64 + b] = c2;
                float h2 = ov * tanhf(c2);
                unsigned short hh = f2bf(h2);
                houtH[b * 512 + j0 + jj] = hh;
                houtL[b * 512 + j0 + jj] = f2bf(h2 - bf2f(hh));
            }
            sync_arrive(&h_cnt[k]);
        }
    } else {
        // ======================== Q pool: logits + argmax ===================
        int qb = blk - 128;
        for (int k = 0; k < NSTEP; ++k) {
            const unsigned short* hH = (k & 1) ? hA_H : hB_H;   // cell(k)'s hout
            const unsigned short* hL = (k & 1) ? hA_L : hB_L;
            sync_wait(&h_cnt[k], 128);
            for (int i = tid; i < 5 * 64; i += 256) skey[i] = 0ull;
            __syncthreads();
            for (int i = wv; i < 5; i += 4) {
                int tile = qb * 5 + i;
                if (tile >= NT16) continue;
                f32x4 acc[4];
                #pragma unroll
                for (int nt = 0; nt < 4; nt++) acc[nt] = (f32x4){0.f, 0.f, 0.f, 0.f};
                int arow = tile * 16 + col;
                if (MODE) {
                    const unsigned short* AH = WoutH + (size_t)arow * 512 + quad * 8;
                    const unsigned short* AL = WoutL + (size_t)arow * 512 + quad * 8;
                    for (int k0 = 0; k0 < 512; k0 += 32) {
                        bf16x8 ah = *(const bf16x8*)(AH + k0);
                        bf16x8 al = *(const bf16x8*)(AL + k0);
                        #pragma unroll
                        for (int nt = 0; nt < 4; nt++) {
                            bf16x8 bh = *(const bf16x8*)(hH + (nt * 16 + col) * 512 + k0 + quad * 8);
                            bf16x8 bl = *(const bf16x8*)(hL + (nt * 16 + col) * 512 + k0 + quad * 8);
                            acc[nt] = MFMA16(ah, bh, acc[nt]);
                            acc[nt] = MFMA16(ah, bl, acc[nt]);
                            acc[nt] = MFMA16(al, bh, acc[nt]);
                        }
                    }
                } else {
                    const unsigned short* A = (const unsigned short*)Wout + (size_t)arow * 512 + quad * 8;
                    for (int k0 = 0; k0 < 512; k0 += 32) {
                        bf16x8 a = *(const bf16x8*)(A + k0);
                        #pragma unroll
                        for (int nt = 0; nt < 4; nt++) {
                            bf16x8 bh = *(const bf16x8*)(hH + (nt * 16 + col) * 512 + k0 + quad * 8);
                            bf16x8 bl = *(const bf16x8*)(hL + (nt * 16 + col) * 512 + k0 + quad * 8);
                            acc[nt] = MFMA16(a, bh, acc[nt]);
                            acc[nt] = MFMA16(a, bl, acc[nt]);
                        }
                    }
                }
                int vbase = tile * 16 + quad * 4;
                #pragma unroll
                for (int nt = 0; nt < 4; nt++) {
                    int b = nt * 16 + col;
                    float bv = NEG_INF;
                    int bi = 0;
                    float vals[4];
                    #pragma unroll
                    for (int r = 0; r < 4; r++) {
                        float bias = MODE ? ((const float*)bout)[vbase + r]
                                          : bf2f(((const unsigned short*)bout)[vbase + r]);
                        float val = acc[nt][r] + bias;
                        vals[r] = val;
                        if (val > bv) { bv = val; bi = vbase + r; }
                    }
                    size_t obase = ((size_t)b * TSZ + (k + 1)) * VSZ;
                    if (MODE) {
                        float4 f4;
                        f4.x = vals[0]; f4.y = vals[1]; f4.z = vals[2]; f4.w = vals[3];
                        *(float4*)((float*)outb + obase + vbase) = f4;
                    } else {
                        us4_t pack;
                        #pragma unroll
                        for (int r = 0; r < 4; r++) pack.s[r] = f2bf(vals[r]);
                        *(us4_t*)((unsigned short*)outb + obase + vbase) = pack;
                    }
                    #pragma unroll
                    for (int off = 16; off < 64; off <<= 1) {
                        float ov = __shfl_xor(bv, off);
                        int oi = __shfl_xor(bi, off);
                        if (ov > bv || (ov == bv && oi < bi)) { bv = ov; bi = oi; }
                    }
                    if (quad == 0) {
                        union { float f; unsigned u; } cv; cv.f = bv;
                        unsigned ob = (cv.u & 0x80000000u) ? ~cv.u : (cv.u | 0x80000000u);
                        skey[i * 64 + b] =
                            ((unsigned long long)ob << 32) |
                            (unsigned long long)(0x7FFFFFFFu - (unsigned)bi);
                    }
                }
            }
            __syncthreads();
            if (tid < 64) {
                unsigned long long best = skey[tid];
                #pragma unroll
                for (int i2 = 1; i2 < 5; i2++) {
                    unsigned long long kk = skey[i2 * 64 + tid];
                    if (kk > best) best = kk;
                }
                bkey[qb * 64 + tid] = best;
            }
            sync_arrive(&q_cnt[k]);
        }
    }
}

__global__ __launch_bounds__(256, 1) void persist2_kernel(
        const void* ctx, const int* labels, const void* emb,
        const void* Wih, const void* Whh, const void* Wout, const void* bout,
        const unsigned short* WoutH, const unsigned short* WoutL,
        const unsigned short* embH, const unsigned short* embL,
        char* outb,
        unsigned short* h0H, unsigned short* h0L,
        unsigned short* h1H, unsigned short* h1L,
        unsigned long long* bkey, int* h_cnt, int* q_cnt,
        const int* usel, const int* flags) {
    __shared__ alignas(16) unsigned short wA[32768];   // 64 KB
    __shared__ float bL[1024];
    __shared__ float cL[256];
    __shared__ float gb[1024];
    __shared__ int predL[64];
    __shared__ unsigned long long rv[256];
    __shared__ unsigned long long skey[320];
    if (flags[0])
        persist2_body<1>(ctx, labels, emb, Wih, Whh, Wout, bout, WoutH, WoutL,
                         embH, embL, outb, h0H, h0L, h1H, h1L, bkey, h_cnt, q_cnt,
                         usel, wA, bL, cL, gb, predL, rv, skey);
    else
        persist2_body<0>(ctx, labels, emb, Wih, Whh, Wout, bout, WoutH, WoutL,
                         embH, embL, outb, h0H, h0L, h1H, h1L, bkey, h_cnt, q_cnt,
                         usel, wA, bL, cL, gb, predL, rv, skey);
}

// ===================== FALLBACK (verified multi-launch path) ================

template<int MODE>
__device__ __forceinline__ void cell_body(
        const void* Wih, const void* Whh,
        const unsigned short* __restrict__ WihH, const unsigned short* __restrict__ WihL,
        const unsigned short* __restrict__ WhhH, const unsigned short* __restrict__ WhhL,
        const char* outb,
        const unsigned short* __restrict__ inpH, const unsigned short* __restrict__ inpL,
        const unsigned short* __restrict__ hH, const unsigned short* __restrict__ hL,
        unsigned short* __restrict__ houtH, unsigned short* __restrict__ houtL,
        float* __restrict__ c) {
    __shared__ float lds[4][16][64];
    const size_t rowb = (MODE == 0) ? 2560000u : 5120000u;
    int tid = threadIdx.x;
    int w = tid >> 6;
    int lane = tid & 63;
    int col = lane & 15;
    int quad = lane >> 4;
    int ko = quad * 8;
    int j0 = blockIdx.x * 16;
    int grow = w * 512 + j0 + col;

    f32x4 acc[4];
    #pragma unroll
    for (int nt = 0; nt < 4; nt++) acc[nt] = (f32x4){0.f, 0.f, 0.f, 0.f};

    if (MODE == 0) {
        const unsigned short* A = (const unsigned short*)Wih + (size_t)grow * 1024 + 512 + ko;
        for (int k0 = 0; k0 < 512; k0 += 32) {
            bf16x8 a = *(const bf16x8*)(A + k0);
            #pragma unroll
            for (int nt = 0; nt < 4; nt++) {
                bf16x8 bh = *(const bf16x8*)(inpH + (nt * 16 + col) * 512 + k0 + ko);
                acc[nt] = MFMA16(a, bh, acc[nt]);
            }
        }
        const unsigned short* A2 = (const unsigned short*)Whh + (size_t)grow * 512 + ko;
        for (int k0 = 0; k0 < 512; k0 += 32) {
            bf16x8 a = *(const bf16x8*)(A2 + k0);
            #pragma unroll
            for (int nt = 0; nt < 4; nt++) {
                bf16x8 bh = *(const bf16x8*)(hH + (nt * 16 + col) * 512 + k0 + ko);
                bf16x8 bl = *(const bf16x8*)(hL + (nt * 16 + col) * 512 + k0 + ko);
                acc[nt] = MFMA16(a, bh, acc[nt]);
                acc[nt] = MFMA16(a, bl, acc[nt]);
            }
        }
    } else if (MODE == 1) {
        const unsigned short* AH = WihH + (size_t)grow * 512 + ko;
        const unsigned short* AL = WihL + (size_t)grow * 512 + ko;
        for (int k0 = 0; k0 < 512; k0 += 32) {
            bf16x8 ah = *(const bf16x8*)(AH + k0);
            bf16x8 al = *(const bf16x8*)(AL + k0);
            #pragma unroll
            for (int nt = 0; nt < 4; nt++) {
                bf16x8 bh = *(const bf16x8*)(inpH + (nt * 16 + col) * 512 + k0 + ko);
                bf16x8 bl = *(const bf16x8*)(inpL + (nt * 16 + col) * 512 + k0 + ko);
                acc[nt] = MFMA16(ah, bh, acc[nt]);
                acc[nt] = MFMA16(ah, bl, acc[nt]);
                acc[nt] = MFMA16(al, bh, acc[nt]);
            }
        }
        const unsigned short* AH2 = WhhH + (size_t)grow * 512 + ko;
        const unsigned short* AL2 = WhhL + (size_t)grow * 512 + ko;
        for (int k0 = 0; k0 < 512; k0 += 32) {
            bf16x8 ah = *(const bf16x8*)(AH2 + k0);
            bf16x8 al = *(const bf16x8*)(AL2 + k0);
            #pragma unroll
            for (int nt = 0; nt < 4; nt++) {
                bf16x8 bh = *(const bf16x8*)(hH + (nt * 16 + col) * 512 + k0 + ko);
                bf16x8 bl = *(const bf16x8*)(hL + (nt * 16 + col) * 512 + k0 + ko);
                acc[nt] = MFMA16(ah, bh, acc[nt]);
                acc[nt] = MFMA16(ah, bl, acc[nt]);
                acc[nt] = MFMA16(al, bh, acc[nt]);
            }
        }
    } else {
        const float* A = (const float*)Wih + (size_t)grow * 1024 + 512 + ko;
        for (int k0 = 0; k0 < 512; k0 += 32) {
            bf16x8 ah, al;
            split8(A + k0, ah, al);
            #pragma unroll
            for (int nt = 0; nt < 4; nt++) {
                bf16x8 bh = *(const bf16x8*)(inpH + (nt * 16 + col) * 512 + k0 + ko);
                bf16x8 bl = *(const bf16x8*)(inpL + (nt * 16 + col) * 512 + k0 + ko);
                acc[nt] = MFMA16(ah, bh, acc[nt]);
                acc[nt] = MFMA16(ah, bl, acc[nt]);
                acc[nt] = MFMA16(al, bh, acc[nt]);
            }
        }
        const float* A2 = (const float*)Whh + (size_t)grow * 512 + ko;
        for (int k0 = 0; k0 < 512; k0 += 32) {
            bf16x8 ah, al;
            split8(A2 + k0, ah, al);
            #pragma unroll
            for (int nt = 0; nt < 4; nt++) {
                bf16x8 bh = *(const bf16x8*)(hH + (nt * 16 + col) * 512 + k0 + ko);
                bf16x8 bl = *(const bf16x8*)(hL + (nt * 16 + col) * 512 + k0 + ko);
                acc[nt] = MFMA16(ah, bh, acc[nt]);
                acc[nt] = MFMA16(ah, bl, acc[nt]);
                acc[nt] = MFMA16(al, bh, acc[nt]);
            }
        }
    }
    #pragma unroll
    for (int nt = 0; nt < 4; nt++) {
        #pragma unroll
        for (int r = 0; r < 4; r++) {
            int row = quad * 4 + r;
            int b = nt * 16 + col;
            float bs = ((const float*)(outb + (size_t)b * rowb))[w * 512 + j0 + row];
            lds[w][row][b] = acc[nt][r] + bs;
        }
    }
    __syncthreads();
    for (int i = tid; i < 1024; i += 256) {
        int jl = i >> 6, b = i & 63, j = j0 + jl;
        float iv = sigmoidf_(lds[0][jl][b]);
        float fv = sigmoidf_(lds[1][jl][b]);
        float gv = tanhf(lds[2][jl][b]);
        float ov = sigmoidf_(lds[3][jl][b]);
        float c2 = fv * c[b * 512 + j] + iv * gv;
        c[b * 512 + j] = c2;
        float h2 = ov * tanhf(c2);
        unsigned short hh = f2bf(h2);
        houtH[b * 512 + j] = hh;
        houtL[b * 512 + j] = f2bf(h2 - bf2f(hh));
    }
}

__global__ __launch_bounds__(256) void cell_kernel(
        const void* Wih, const void* Whh, const char* outb,
        const unsigned short* WihH, const unsigned short* WihL,
        const unsigned short* WhhH, const unsigned short* WhhL,
        const unsigned short* inpH, const unsigned short* inpL,
        const unsigned short* hH, const unsigned short* hL,
        unsigned short* houtH, unsigned short* houtL,
        float* c, const int* flags, int presplit) {
    if (flags[0] == 0)
        cell_body<0>(Wih, Whh, WihH, WihL, WhhH, WhhL, outb, inpH, inpL, hH, hL, houtH, houtL, c);
    else if (presplit)
        cell_body<1>(Wih, Whh, WihH, WihL, WhhH, WhhL, outb, inpH, inpL, hH, hL, houtH, houtL, c);
    else
        cell_body<2>(Wih, Whh, WihH, WihL, WhhH, WhhL, outb, inpH, inpL, hH, hL, houtH, houtL, c);
}

template<int MODE>
__device__ __forceinline__ void out_body(
        const void* Wout, const unsigned short* __restrict__ WoutH,
        const unsigned short* __restrict__ WoutL, const void* bout,
        const unsigned short* __restrict__ hH, const unsigned short* __restrict__ hL,
        void* outv, float* pval, int* pidx, int t) {
    __shared__ float sv[4][64];
    __shared__ int   si[4][64];
    int tid = threadIdx.x;
    int w = tid >> 6, lane = tid & 63, col = lane & 15, quad = lane >> 4;
    int ko = quad * 8;
    int v0 = blockIdx.x * 64 + w * 16;
    int arow = imin_(v0 + col, VSZ - 1);

    f32x4 acc[4];
    #pragma unroll
    for (int nt = 0; nt < 4; nt++) acc[nt] = (f32x4){0.f, 0.f, 0.f, 0.f};

    if (MODE == 0) {
        const unsigned short* A = (const unsigned short*)Wout + (size_t)arow * 512 + ko;
        for (int k0 = 0; k0 < 512; k0 += 32) {
            bf16x8 a = *(const bf16x8*)(A + k0);
            #pragma unroll
            for (int nt = 0; nt < 4; nt++) {
                bf16x8 bh = *(const bf16x8*)(hH + (nt * 16 + col) * 512 + k0 + ko);
                bf16x8 bl = *(const bf16x8*)(hL + (nt * 16 + col) * 512 + k0 + ko);
                acc[nt] = MFMA16(a, bh, acc[nt]);
                acc[nt] = MFMA16(a, bl, acc[nt]);
            }
        }
    } else if (MODE == 1) {
        const unsigned short* AH = WoutH + (size_t)arow * 512 + ko;
        const unsigned short* AL = WoutL + (size_t)arow * 512 + ko;
        for (int k0 = 0; k0 < 512; k0 += 32) {
            bf16x8 ah = *(const bf16x8*)(AH + k0);
            bf16x8 al = *(const bf16x8*)(AL + k0);
            #pragma unroll
            for (int nt = 0; nt < 4; nt++) {
                bf16x8 bh = *(const bf16x8*)(hH + (nt * 16 + col) * 512 + k0 + ko);
                bf16x8 bl = *(const bf16x8*)(hL + (nt * 16 + col) * 512 + k0 + ko);
                acc[nt] = MFMA16(ah, bh, acc[nt]);
                acc[nt] = MFMA16(ah, bl, acc[nt]);
                acc[nt] = MFMA16(al, bh, acc[nt]);
            }
        }
    } else {
        const float* A = (const float*)Wout + (size_t)arow * 512 + ko;
        for (int k0 = 0; k0 < 512; k0 += 32) {
            bf16x8 ah, al;
            split8(A + k0, ah, al);
            #pragma unroll
            for (int nt = 0; nt < 4; nt++) {
                bf16x8 bh = *(const bf16x8*)(hH + (nt * 16 + col) * 512 + k0 + ko);
                bf16x8 bl = *(const bf16x8*)(hL + (nt * 16 + col) * 512 + k0 + ko);
                acc[nt] = MFMA16(ah, bh, acc[nt]);
                acc[nt] = MFMA16(ah, bl, acc[nt]);
                acc[nt] = MFMA16(al, bh, acc[nt]);
            }
        }
    }

    int vbase = v0 + quad * 4;
    #pragma unroll
    for (int nt = 0; nt < 4; nt++) {
        int b = nt * 16 + col;
        float bv = NEG_INF;
        int bi = 0;
        float vals[4];
        #pragma unroll
        for (int r = 0; r < 4; r++) {
            int v = vbase + r;
            int vc = imin_(v, VSZ - 1);
            float bias = (MODE != 0) ? ((const float*)bout)[vc]
                                     : bf2f(((const unsigned short*)bout)[vc]);
            float val = acc[nt][r] + bias;
            vals[r] = val;
            if (v < VSZ && val > bv) { bv = val; bi = v; }
        }
        size_t obase = ((size_t)b * TSZ + t) * VSZ;
        if (MODE == 0) {
            us4_t pack;
            #pragma unroll
            for (int r = 0; r < 4; r++) pack.s[r] = f2bf(vals[r]);
            if (vbase + 3 < VSZ) {
                *(us4_t*)((unsigned short*)outv + obase + vbase) = pack;
            } else {
                for (int r = 0; r < 4; r++)
                    if (vbase + r < VSZ) ((unsigned short*)outv)[obase + vbase + r] = pack.s[r];
            }
        } else {
            if (vbase + 3 < VSZ) {
                float4 f4; f4.x = vals[0]; f4.y = vals[1]; f4.z = vals[2]; f4.w = vals[3];
                *(float4*)((float*)outv + obase + vbase) = f4;
            } else {
                for (int r = 0; r < 4; r++)
                    if (vbase + r < VSZ) ((float*)outv)[obase + vbase + r] = vals[r];
            }
        }
        #pragma unroll
        for (int off = 16; off < 64; off <<= 1) {
            float ov = __shfl_xor(bv, off);
            int oi = __shfl_xor(bi, off);
            if (ov > bv || (ov == bv && oi < bi)) { bv = ov; bi = oi; }
        }
        if (quad == 0) { sv[w][b] = bv; si[w][b] = bi; }
    }
    __syncthreads();
    if (tid < 64) {
        float bv = sv[0][tid];
        int bi = si[0][tid];
        #pragma unroll
        for (int w2 = 1; w2 < 4; w2++) {
            float v2 = sv[w2][tid];
            int i2 = si[w2][tid];
            if (v2 > bv || (v2 == bv && i2 < bi)) { bv = v2; bi = i2; }
        }
        pval[blockIdx.x * 64 + tid] = bv;
        pidx[blockIdx.x * 64 + tid] = bi;
    }
}

__global__ __launch_bounds__(256) void out_kernel(
        const void* Wout, const unsigned short* WoutH, const unsigned short* WoutL,
        const void* bout, const unsigned short* hH, const unsigned short* hL,
        void* outv, float* pval, int* pidx, int t, const int* flags, int presplit) {
    if (flags[0] == 0)
        out_body<0>(Wout, WoutH, WoutL, bout, hH, hL, outv, pval, pidx, t);
    else if (presplit)
        out_body<1>(Wout, WoutH, WoutL, bout, hH, hL, outv, pval, pidx, t);
    else
        out_body<2>(Wout, WoutH, WoutL, bout, hH, hL, outv, pval, pidx, t);
}

__global__ __launch_bounds__(1024) void pick_kernel(
        const float* __restrict__ pval, const int* __restrict__ pidx,
        const void* emb, const int* __restrict__ labels,
        const int* __restrict__ usel, unsigned short* __restrict__ inpH,
        unsigned short* __restrict__ inpL, int t, const int* __restrict__ flags) {
    __shared__ float svv[64][4];
    __shared__ int   sii[64][4];
    __shared__ int   pred[64];
    int mode = flags[0];
    int tid = threadIdx.x;
    if (tid < 256) {
        int b = tid >> 2, q = tid & 3;
        float bv = NEG_INF;
        int bi = 0;
        for (int wt = q; wt < NTILE; wt += 4) {
            float v = pval[wt * 64 + b];
            int ix = pidx[wt * 64 + b];
            if (v > bv || (v == bv && ix < bi)) { bv = v; bi = ix; }
        }
        svv[b][q] = bv;
        sii[b][q] = bi;
    }
    __syncthreads();
    if (tid < 64) {
        float v = svv[tid][0];
        int ix = sii[tid][0];
        #pragma unroll
        for (int q2 = 1; q2 < 4; q2++) {
            float v2 = svv[tid][q2];
            int i2 = sii[tid][q2];
            if (v2 > v || (v2 == v && i2 < ix)) { v = v2; ix = i2; }
        }
        int lab = labels[tid * TSZ + t];
        int p = usel[t] ? lab : ix;
        pred[tid] = imin_(imax_(p, 0), VSZ - 1);
    }
    __syncthreads();
    for (int i = tid; i < BSZ * ESZ / 4; i += 1024) {
        int b2 = i >> 7;
        int ch = i & 127;
        if (mode) {
            float4 f = ((const float4*)emb)[(size_t)pred[b2] * 128 + ch];
            float vv[4] = {f.x, f.y, f.z, f.w};
            us4_t h4, l4;
            #pragma unroll
            for (int r = 0; r < 4; r++) {
                unsigned short hh = f2bf(vv[r]);
                h4.s[r] = hh;
                l4.s[r] = f2bf(vv[r] - bf2f(hh));
            }
            *(us4_t*)(inpH + (size_t)b2 * 512 + ch * 4) = h4;
            *(us4_t*)(inpL + (size_t)b2 * 512 + ch * 4) = l4;
        } else {
            us4_t u = ((const us4_t*)emb)[(size_t)pred[b2] * 128 + ch];
            *(us4_t*)(inpH + (size_t)b2 * 512 + ch * 4) = u;
        }
    }
}

// ---- zero the t=0 output slice (also wipes the base scratch living there) ----
__global__ void zero_t0_kernel(char* outb, const int* flags) {
    int i = blockIdx.x * 256 + threadIdx.x;
    uint4 z = make_uint4(0u, 0u, 0u, 0u);
    if (flags[0]) {
        if (i < 160000) {
            int b = i / 2500, ch = i - b * 2500;
            *((uint4*)(outb + (size_t)b * 5120000u) + ch) = z;
        }
    } else {
        if (i < 80000) {
            int b = i / 1250, ch = i - b * 1250;
            *((uint4*)(outb + (size_t)b * 2560000u) + ch) = z;
        }
    }
}

extern "C" void kernel_launch(void* const* d_in, const int* in_sizes, int n_in,
                              void* d_out, int out_size, void* d_ws, size_t ws_size,
                              hipStream_t stream) {
    const void* ctx      = d_in[0];
    const int*  labels   = (const int*)d_in[1];
    const void* usel_raw = d_in[2];
    const void* emb      = d_in[3];
    const void* Wih      = d_in[4];
    const void* Whh      = d_in[5];
    const void* bih      = d_in[6];
    const void* bhh      = d_in[7];
    const void* Wout     = d_in[8];
    const void* bout     = d_in[9];
    char* outb = (char*)d_out;

    char* ws = (char*)d_ws;
    // small region
    int*   flags = (int*)ws;                               // 256 B
    int*   usel  = (int*)(ws + 256);                       // 512 B
    float* pval  = (float*)(ws + 1024);                    // 40192 (fallback)
    int*   pidx  = (int*)(ws + 41216);                     // 40192 (fallback)
    float* c     = (float*)(ws + 81408);                   // 131072 (fallback)
    unsigned short* h0H  = (unsigned short*)(ws + 212480); // 65536
    unsigned short* h0L  = (unsigned short*)(ws + 278016); // 65536
    unsigned short* h1H  = (unsigned short*)(ws + 343552); // 65536
    unsigned short* h1L  = (unsigned short*)(ws + 409088); // 65536
    unsigned short* inpH = (unsigned short*)(ws + 474624); // 65536 (fallback)
    unsigned short* inpL = (unsigned short*)(ws + 540160); // 65536 (fallback)
    // persistent-path region
    int* h_cnt = (int*)(ws + 605696);                      // 1024
    int* q_cnt = (int*)(ws + 606720);                      // 1024
    unsigned long long* bkey = (unsigned long long*)(ws + 607744);  // 65536
    unsigned short* WoutH = (unsigned short*)(ws + 673280);     // 10,240,000
    unsigned short* WoutL = (unsigned short*)(ws + 10913280);   // 10,240,000
    unsigned short* WihH  = (unsigned short*)(ws + 21153280);   //  2,097,152
    unsigned short* WihL  = (unsigned short*)(ws + 23250432);   //  2,097,152
    unsigned short* WhhH  = (unsigned short*)(ws + 25347584);   //  2,097,152
    unsigned short* WhhL  = (unsigned short*)(ws + 27444736);   //  2,097,152
    unsigned short* embH  = (unsigned short*)(ws + 29541888);   // 10,240,000
    unsigned short* embL  = (unsigned short*)(ws + 39781888);   // 10,240,000
    const size_t WS_FULL = 50021888u;   // persistent path (incl. emb presplit)
    const size_t WS_PRE  = 29541888u;   // multi-launch with weight presplit
    int full = (ws_size >= WS_FULL) ? 1 : 0;
    int pre  = (ws_size >= WS_PRE) ? 1 : 0;

    det_kernel<<<1, 256, 0, stream>>>(Wout, usel_raw, flags, usel, h_cnt, q_cnt);
    if (pre) {
        // no-ops in mode 0 (kernels early-out on flags)
        splitw_kernel<<<2500, 256, 0, stream>>>((const float*)Wout, WoutH, WoutL,
                                                VSZ * 64, 512, 0, flags);
        splitw_kernel<<<512, 256, 0, stream>>>((const float*)Wih, WihH, WihL,
                                               2048 * 64, 1024, 512, flags);
        splitw_kernel<<<512, 256, 0, stream>>>((const float*)Whh, WhhH, WhhL,
                                               2048 * 64, 512, 0, flags);
    }
    if (full) {
        splitw_kernel<<<2500, 256, 0, stream>>>((const float*)emb, embH, embL,
                                                VSZ * 64, 512, 0, flags);
    }
    base_kernel<<<512, 256, 0, stream>>>(ctx, Wih, bih, bhh, flags, outb);
    init_kernel<<<128, 256, 0, stream>>>(ctx, emb, labels, flags, c, h0H, h0L, inpH, inpL);

    int did_persist = 0;
    if (full) {
        const void* a0 = ctx; const int* a1 = labels; const void* a2 = emb;
        const void* a3 = Wih; const void* a4 = Whh; const void* a5 = Wout;
        const void* a6 = bout;
        const unsigned short* a7 = WoutH; const unsigned short* a8 = WoutL;
        const unsigned short* a9 = embH;  const unsigned short* a10 = embL;
        char* a11 = outb;
        unsigned short* a12 = h0H; unsigned short* a13 = h0L;
        unsigned short* a14 = h1H; unsigned short* a15 = h1L;
        unsigned long long* a16 = bkey; int* a17 = h_cnt; int* a18 = q_cnt;
        const int* a19 = usel; const int* a20 = flags;
        void* kargs[] = {&a0, &a1, &a2, &a3, &a4, &a5, &a6, &a7, &a8, &a9, &a10,
                         &a11, &a12, &a13, &a14, &a15, &a16, &a17, &a18, &a19, &a20};
        hipError_t e = hipLaunchCooperativeKernel(persist2_kernel, dim3(256), dim3(256),
                                                  kargs, 0u, stream);
        if (e == hipSuccess) did_persist = 1;
    }
    if (!did_persist) {
        for (int k = 0; k < NSTEP; ++k) {
            unsigned short* hinH  = (k & 1) ? h1H : h0H;
            unsigned short* hinL  = (k & 1) ? h1L : h0L;
            unsigned short* houtH = (k & 1) ? h0H : h1H;
            unsigned short* houtL = (k & 1) ? h0L : h1L;
            cell_kernel<<<32, 256, 0, stream>>>(Wih, Whh, outb, WihH, WihL, WhhH, WhhL,
                                                inpH, inpL, hinH, hinL, houtH, houtL,
                                                c, flags, pre);
            out_kernel<<<NTILE, 256, 0, stream>>>(Wout, WoutH, WoutL, bout, houtH, houtL,
                                                  (void*)outb, pval, pidx, k + 1,
                                                  flags, pre);
            pick_kernel<<<1, 1024, 0, stream>>>(pval, pidx, emb, labels, usel, inpH, inpL,
                                                k + 1, flags);
        }
    }
    zero_t0_kernel<<<626, 256, 0, stream>>>(outb, flags);
}